// Round 4
// baseline (98.787 us; speedup 1.0000x reference)
//
#include <hip/hip_runtime.h>
#include <hip/hip_cooperative_groups.h>

namespace cg = cooperative_groups;

#define N_NODES 4096
#define DEG 8
#define N_EDGES (N_NODES * DEG)
#define FEAT 64
#define HID 32
#define N_CLASSES 2
#define N_SEEDS 512

#define NBLK 128
#define NTHR 512
#define T_TOT (NBLK * NTHR)   // 65536 threads

__global__ __launch_bounds__(NTHR) void fused_hgnn(
        const float* __restrict__ X,  const float* __restrict__ W1,
        const float* __restrict__ b1, const float* __restrict__ W2,
        const float* __restrict__ b2, const int* __restrict__ ind,
        const int* __restrict__ seed,
        float* __restrict__ Z1, float* __restrict__ A1,
        float* __restrict__ Z2, float* __restrict__ A2,
        float* __restrict__ out) {
    cg::grid_group grid = cg::this_grid();
    int tid = blockIdx.x * blockDim.x + threadIdx.x;

    __shared__ float W1s[FEAT * HID];
    for (int i = threadIdx.x; i < FEAT * HID; i += blockDim.x) W1s[i] = W1[i];
    __syncthreads();

    // ---- P1: Z1 = X@W1 ; zero A1, A2 ----------------------------------
#pragma unroll
    for (int r = 0; r < 2; ++r) {
        int idx = tid + r * T_TOT;          // 0..131071  (= n*32 + h)
        int n = idx >> 5, h = idx & 31;
        const float* xrow = X + n * FEAT;
        float acc = 0.f;
#pragma unroll
        for (int k = 0; k < FEAT; ++k) acc += xrow[k] * W1s[k * HID + h];
        Z1[idx] = acc;
        A1[idx] = 0.f;
    }
    if (tid < N_NODES * N_CLASSES) A2[tid] = 0.f;
    grid.sync();

    // ---- P2: hop-1 message pass into A1 (own in register, reverse atomic)
#pragma unroll
    for (int r = 0; r < 2; ++r) {
        int idx = tid + r * T_TOT;
        int n = idx >> 5, h = idx & 31;
        float zn = Z1[idx];
        float own = 0.f;
        const int* row = ind + n * DEG;
#pragma unroll
        for (int d = 0; d < DEG; ++d) {
            int v = row[d];
            if (v == n) {
                own += zn;                         // self-loop: counted once
            } else {
                float m = zn + Z1[v * HID + h];
                own += m;
                atomicAdd(&A1[v * HID + h], m);    // reverse scatter
            }
        }
        atomicAdd(&A1[idx], own);
    }
    grid.sync();

    // ---- P3a: Z2[n][c] = relu(A1[n]+b1) @ W2 --------------------------
    if (tid < N_NODES * N_CLASSES) {
        int n = tid >> 1, c = tid & 1;
        const float* a = A1 + n * HID;
        float z = 0.f;
#pragma unroll
        for (int k = 0; k < HID; ++k) {
            float hk = a[k] + b1[k];
            hk = hk > 0.f ? hk : 0.f;
            z += hk * W2[k * N_CLASSES + c];
        }
        Z2[tid] = z;
    }
    grid.sync();

    // ---- P3b: hop-2 message pass into A2 ------------------------------
    if (tid < N_NODES * N_CLASSES) {
        int n = tid >> 1, c = tid & 1;
        float zn = Z2[tid];
        float own = 0.f;
        const int* row = ind + n * DEG;
#pragma unroll
        for (int d = 0; d < DEG; ++d) {
            int v = row[d];
            if (v == n) {
                own += zn;
            } else {
                float m = zn + Z2[v * N_CLASSES + c];
                own += m;
                atomicAdd(&A2[v * N_CLASSES + c], m);
            }
        }
        atomicAdd(&A2[tid], own);
    }
    grid.sync();

    // ---- P4: seed gather ----------------------------------------------
    if (tid < N_SEEDS * N_CLASSES) {
        int s = tid >> 1, c = tid & 1;
        out[tid] = A2[seed[s] * N_CLASSES + c] + b2[c];
    }
}

extern "C" void kernel_launch(void* const* d_in, const int* in_sizes, int n_in,
                              void* d_out, int out_size, void* d_ws, size_t ws_size,
                              hipStream_t stream) {
    // setup_inputs order: sub_indptr, sub_indices, X, W1, b1, W2, b2, seed_idx
    const int*   ind  = (const int*)d_in[1];
    const float* X    = (const float*)d_in[2];
    const float* W1   = (const float*)d_in[3];
    const float* b1   = (const float*)d_in[4];
    const float* W2   = (const float*)d_in[5];
    const float* b2   = (const float*)d_in[6];
    const int*   seed = (const int*)d_in[7];
    float* out = (float*)d_out;

    char* ws = (char*)d_ws;
    float* Z1 = (float*)(ws);                              // 512 KiB
    float* A1 = (float*)(ws + 512 * 1024);                 // 512 KiB
    float* Z2 = (float*)(ws + 1024 * 1024);                // 32 KiB
    float* A2 = (float*)(ws + 1024 * 1024 + 32 * 1024);    // 32 KiB

    void* args[] = { (void*)&X, (void*)&W1, (void*)&b1, (void*)&W2, (void*)&b2,
                     (void*)&ind, (void*)&seed,
                     (void*)&Z1, (void*)&A1, (void*)&Z2, (void*)&A2, (void*)&out };
    hipLaunchCooperativeKernel((const void*)fused_hgnn,
                               dim3(NBLK), dim3(NTHR), args, 0, stream);
}

// Round 5
// 32.484 us; speedup vs baseline: 3.0411x; 3.0411x over previous
//
#include <hip/hip_runtime.h>

#define N_NODES 4096
#define DEG 8
#define N_EDGES (N_NODES * DEG)
#define FEAT 64
#define HID 32
#define NC 2
#define N_SEEDS 512
#define BCAP 40   // max in-degree bucket; Poisson(8) tail P(>=40) ~ 1e-14

// ws layout:
//   Z1  [0,      512K)  float[4096*32]
//   Z2  [512K,   544K)  float[4096*2]
//   r   [544K,   560K)  int[4096]      (in-degree / build counter)
//   bkt [560K,   888K)  ushort[4096*BCAP]  (incoming-edge source nodes)

// K1: Z1 = X @ W1 (W1 in LDS, float4 X loads); zero the in-degree counters.
__global__ __launch_bounds__(256) void k1_gemm(const float* __restrict__ X,
                                               const float* __restrict__ W1,
                                               float* __restrict__ Z1,
                                               int* __restrict__ r) {
    __shared__ float W1s[FEAT * HID];
    int t = threadIdx.x;
    for (int i = t; i < FEAT * HID; i += 256) W1s[i] = W1[i];
    __syncthreads();
    int idx = blockIdx.x * 256 + t;        // n*32 + h
    int n = idx >> 5, h = idx & 31;
    const float4* x4 = (const float4*)(X + n * FEAT);
    float acc = 0.f;
#pragma unroll
    for (int q = 0; q < 16; ++q) {
        float4 xv = x4[q];
        acc += xv.x * W1s[(4 * q + 0) * HID + h];
        acc += xv.y * W1s[(4 * q + 1) * HID + h];
        acc += xv.z * W1s[(4 * q + 2) * HID + h];
        acc += xv.w * W1s[(4 * q + 3) * HID + h];
    }
    Z1[idx] = acc;
    if (idx < N_NODES) r[idx] = 0;
}

// K2: build transpose adjacency — for each non-self edge e=(u -> v=ind[e]),
// append u to v's incoming bucket. 32K int atomics total.
__global__ __launch_bounds__(256) void k2_build(const int* __restrict__ ind,
                                                int* __restrict__ r,
                                                unsigned short* __restrict__ bkt) {
    int e = blockIdx.x * 256 + threadIdx.x;   // 0..32767
    int u = e >> 3;                            // uniform CSR: indptr[n]=n*DEG
    int v = ind[e];
    if (v != u) {
        int slot = atomicAdd(&r[v], 1);
        bkt[v * BCAP + slot] = (unsigned short)u;
    }
}

// K3: hop-1 gather A1[n][h] = (8+r)·Z1[n][h] + Σ_out Z1[v][h] + Σ_in Z1[u][h]
// (register only), then fused Z2[n][c] = relu(A1+b1) @ W2 via 32-lane reduce.
__global__ __launch_bounds__(256) void k3_hop1(const float* __restrict__ Z1,
                                               const int* __restrict__ ind,
                                               const int* __restrict__ r,
                                               const unsigned short* __restrict__ bkt,
                                               const float* __restrict__ b1,
                                               const float* __restrict__ W2,
                                               float* __restrict__ Z2) {
    int idx = blockIdx.x * 256 + threadIdx.x;  // n*32 + h
    int n = idx >> 5, h = idx & 31;
    float zn = Z1[idx];
    int rn = r[n];
    float a = (float)(DEG + rn) * zn;
    const int* row = ind + n * DEG;
#pragma unroll
    for (int d = 0; d < DEG; ++d) {
        int v = row[d];
        if (v != n) a += Z1[v * HID + h];      // outgoing non-self
    }
    const unsigned short* bn = bkt + n * BCAP;
    for (int j = 0; j < rn; ++j)
        a += Z1[(int)bn[j] * HID + h];         // incoming non-self
    float hk = a + b1[h];
    hk = hk > 0.f ? hk : 0.f;
    float t0 = hk * W2[h * NC + 0];
    float t1 = hk * W2[h * NC + 1];
#pragma unroll
    for (int off = 16; off > 0; off >>= 1) {   // reduce over the 32-lane h-group
        t0 += __shfl_down(t0, off, 32);
        t1 += __shfl_down(t1, off, 32);
    }
    if (h == 0) *(float2*)(Z2 + n * NC) = make_float2(t0, t1);
}

// K4: hop-2 evaluated ONLY at seed nodes, fused with output gather + b2.
__global__ __launch_bounds__(256) void k4_out(const float* __restrict__ Z2,
                                              const int* __restrict__ ind,
                                              const int* __restrict__ r,
                                              const unsigned short* __restrict__ bkt,
                                              const float* __restrict__ b2,
                                              const int* __restrict__ seed,
                                              float* __restrict__ out) {
    int idx = blockIdx.x * 256 + threadIdx.x;  // s*2 + c
    if (idx >= N_SEEDS * NC) return;
    int s = idx >> 1, c = idx & 1;
    int n = seed[s];
    int rn = r[n];
    float a = (float)(DEG + rn) * Z2[n * NC + c];
    const int* row = ind + n * DEG;
#pragma unroll
    for (int d = 0; d < DEG; ++d) {
        int v = row[d];
        if (v != n) a += Z2[v * NC + c];
    }
    const unsigned short* bn = bkt + n * BCAP;
    for (int j = 0; j < rn; ++j)
        a += Z2[(int)bn[j] * NC + c];
    out[idx] = a + b2[c];
}

extern "C" void kernel_launch(void* const* d_in, const int* in_sizes, int n_in,
                              void* d_out, int out_size, void* d_ws, size_t ws_size,
                              hipStream_t stream) {
    // setup_inputs order: sub_indptr, sub_indices, X, W1, b1, W2, b2, seed_idx
    const int*   ind  = (const int*)d_in[1];
    const float* X    = (const float*)d_in[2];
    const float* W1   = (const float*)d_in[3];
    const float* b1   = (const float*)d_in[4];
    const float* W2   = (const float*)d_in[5];
    const float* b2   = (const float*)d_in[6];
    const int*   seed = (const int*)d_in[7];
    float* out = (float*)d_out;

    char* ws = (char*)d_ws;
    float*          Z1  = (float*)(ws);
    float*          Z2  = (float*)(ws + 512 * 1024);
    int*            r   = (int*)(ws + 544 * 1024);
    unsigned short* bkt = (unsigned short*)(ws + 560 * 1024);

    k1_gemm <<<(N_NODES * HID) / 256, 256, 0, stream>>>(X, W1, Z1, r);
    k2_build<<<N_EDGES / 256,        256, 0, stream>>>(ind, r, bkt);
    k3_hop1 <<<(N_NODES * HID) / 256, 256, 0, stream>>>(Z1, ind, r, bkt, b1, W2, Z2);
    k4_out  <<<(N_SEEDS * NC + 255) / 256, 256, 0, stream>>>(Z2, ind, r, bkt, b2, seed, out);
}